// Round 1
// baseline (333.052 us; speedup 1.0000x reference)
//
#include <hip/hip_runtime.h>
#include <math.h>

// Problem constants (fixed by reference setup_inputs)
#define B_SZ  2048
#define DIN   64
#define DOUT  64
#define NH    32
#define NF    7
#define NBI   (B_SZ * DIN)      // 131072, per-feature plane size

// Main-kernel tiling
#define IG    4                 // i's (Din indices) per block
#define NGRP  (DIN / IG)        // 16 partial groups
#define BCH   32                // b's per block (4 waves x 8 b/thread)

// ---------------------------------------------------------------------------
// Kernel 1: features  f[b,i,:] = [x, sin x, sin 2x, sin 4x, cos x, cos 2x, cos 4x]
// stored SoA: feats[f][i][b]  (f*131072 + i*2048 + b) so the main kernel can
// load 4 consecutive b as one float4.
// ---------------------------------------------------------------------------
__global__ __launch_bounds__(256) void feats_kernel(const float* __restrict__ x,
                                                    float* __restrict__ feats) {
    int g = blockIdx.x * 256 + threadIdx.x;   // g = i*2048 + b
    int i = g >> 11;
    int b = g & 2047;
    float xv = x[b * DIN + i];
    float s1, c1;
    __sincosf(xv, &s1, &c1);
    float s2 = 2.0f * s1 * c1;
    float c2 = 1.0f - 2.0f * s1 * s1;
    float s4 = 2.0f * s2 * c2;
    float c4 = 1.0f - 2.0f * s2 * s2;
    feats[0 * NBI + g] = xv;
    feats[1 * NBI + g] = s1;
    feats[2 * NBI + g] = s2;
    feats[3 * NBI + g] = s4;
    feats[4 * NBI + g] = c1;
    feats[5 * NBI + g] = c2;
    feats[6 * NBI + g] = c4;
}

// ---------------------------------------------------------------------------
// Kernel 2: main compute. Block = 256 threads = 4 waves; lane = o (Dout index),
// wave handles 8 b's. Block covers (IG i's) x (32 b's); grid = 16 igroups x 64
// b-chunks = 1024 blocks. W1 (+folded B1) staged per-i in LDS, h split in two
// 16-row phases to stay at 40 KB LDS (4 blocks/CU).
// LDS layout: sW1[row][o'] with row = hloc*8 + f (f==7 holds B1), swizzled
// o' = (o + row) & 63 -> compute reads hit each bank exactly 2x (free).
// ---------------------------------------------------------------------------
__global__ __launch_bounds__(256, 4) void main_kernel(
        const float* __restrict__ W1, const float* __restrict__ W2,
        const float* __restrict__ B1, const float* __restrict__ B2,
        const float* __restrict__ feats, float* __restrict__ partials) {
    __shared__ float sW1[128 * 64];   // 32 KB: 16 h x 8 (7 w1 + b1) x 64 o
    __shared__ float sW2[32 * 64];    // 8 KB

    const int tid = threadIdx.x;
    const int o   = tid & 63;
    const int w   = tid >> 6;
    const int bchunk = blockIdx.x & 63;   // 64 chunks of 32 b
    const int ig     = blockIdx.x >> 6;   // 16 i-groups
    const int bbase  = bchunk * BCH + w * 8;

    float phi[8];
#pragma unroll
    for (int k = 0; k < 8; ++k) phi[k] = 0.0f;

    for (int ii = 0; ii < IG; ++ii) {
        const int i = ig * IG + ii;
        const float* __restrict__ W1i = W1 + i * (DOUT * NH * NF);  // 14336
        const float b2 = B2[i * 64 + o];

        for (int ph = 0; ph < 2; ++ph) {
            const int h0 = ph * 16;
            __syncthreads();   // previous compute done before overwrite
            // ---- stage W1 half: per o, 112 contiguous floats (h0..h0+15, f 0..6)
            for (int g = tid; g < 64 * 112; g += 256) {
                int oo = g / 112;
                int r  = g % 112;          // r = hloc*7 + f
                int hh = r / 7;
                int f  = r % 7;
                int row = hh * 8 + f;
                sW1[row * 64 + ((oo + row) & 63)] = W1i[oo * 224 + h0 * 7 + r];
            }
            // ---- stage B1 half into f==7 rows
            for (int g = tid; g < 64 * 16; g += 256) {
                int oo = g >> 4;
                int hh = g & 15;
                int row = hh * 8 + 7;
                sW1[row * 64 + ((oo + row) & 63)] = B1[i * 2048 + oo * 32 + h0 + hh];
            }
            // ---- stage W2 once per i
            if (ph == 0) {
                for (int g = tid; g < 2048; g += 256) {
                    int oo = g >> 5;
                    int hh = g & 31;
                    sW2[hh * 64 + ((oo + hh) & 63)] = W2[i * 2048 + g];
                }
            }
            __syncthreads();

            // ---- compute: 2 tiles of 4 b
            for (int t = 0; t < 2; ++t) {
                const int b0 = bbase + t * 4;
                const float* fp = feats + i * 2048 + b0;
                float F[7][4];
#pragma unroll
                for (int j = 0; j < 7; ++j) {
                    float4 v = *(const float4*)(fp + j * NBI);
                    F[j][0] = v.x; F[j][1] = v.y; F[j][2] = v.z; F[j][3] = v.w;
                }
#pragma unroll 4
                for (int hh = 0; hh < 16; ++hh) {
                    const int hg = h0 + hh;
                    float wv[7];
#pragma unroll
                    for (int j = 0; j < 7; ++j) {
                        int row = hh * 8 + j;
                        wv[j] = sW1[row * 64 + ((o + row) & 63)];
                    }
                    float b1v;
                    {
                        int row = hh * 8 + 7;
                        b1v = sW1[row * 64 + ((o + row) & 63)];
                    }
                    const float w2h = sW2[hg * 64 + ((o + hg) & 63)];
#pragma unroll
                    for (int k = 0; k < 4; ++k) {
                        float a = b1v;
#pragma unroll
                        for (int j = 0; j < 7; ++j) a += wv[j] * F[j][k];
                        // silu(a) = a / (1 + e^-a); use fast exp + v_rcp
                        float e = __expf(-a);
                        float s = a * __builtin_amdgcn_rcpf(1.0f + e);
                        phi[t * 4 + k] += s * w2h;
                    }
                }
            }
        }
#pragma unroll
        for (int k = 0; k < 8; ++k) phi[k] += b2;   // B2 once per (i,o,b)
    }

    // write partials[ig][b][o], coalesced over o
    float* pp = partials + ig * (B_SZ * DOUT);
#pragma unroll
    for (int k = 0; k < 8; ++k) {
        pp[(bbase + k) * 64 + o] = phi[k];
    }
}

// ---------------------------------------------------------------------------
// Kernel 3: reduce the 16 i-group partials -> out[b][o]
// ---------------------------------------------------------------------------
__global__ __launch_bounds__(256) void reduce_kernel(const float* __restrict__ partials,
                                                     float* __restrict__ out) {
    int t = blockIdx.x * 256 + threadIdx.x;   // < 131072
    float s = 0.0f;
#pragma unroll
    for (int g = 0; g < NGRP; ++g) s += partials[g * (B_SZ * DOUT) + t];
    out[t] = s;
}

extern "C" void kernel_launch(void* const* d_in, const int* in_sizes, int n_in,
                              void* d_out, int out_size, void* d_ws, size_t ws_size,
                              hipStream_t stream) {
    const float* x  = (const float*)d_in[0];
    const float* W1 = (const float*)d_in[1];
    const float* W2 = (const float*)d_in[2];
    const float* B1 = (const float*)d_in[3];
    const float* B2 = (const float*)d_in[4];
    float* out = (float*)d_out;

    float* feats    = (float*)d_ws;                                  // 7*131072*4 = 3.67 MB
    float* partials = (float*)((char*)d_ws + (size_t)NF * NBI * 4);  // 16*131072*4 = 8 MB

    feats_kernel<<<NBI / 256, 256, 0, stream>>>(x, feats);
    main_kernel<<<NGRP * (B_SZ / BCH), 256, 0, stream>>>(W1, W2, B1, B2, feats, partials);
    reduce_kernel<<<(B_SZ * DOUT) / 256, 256, 0, stream>>>(partials, out);
}

// Round 2
// 179.071 us; speedup vs baseline: 1.8599x; 1.8599x over previous
//
#include <hip/hip_runtime.h>
#include <math.h>

// Problem constants (fixed by reference setup_inputs)
#define B_SZ  2048
#define DIN   64
#define DOUT  64
#define NH    32
#define NF    7
#define NBI   (B_SZ * DIN)      // 131072, per-feature plane size

// Main-kernel tiling
#define IG    4                 // i's (Din indices) per block
#define NGRP  (DIN / IG)        // 16 partial groups
#define BCH   32                // b's per block (4 waves x 8 b/thread)

// Per-i prepped image: [ph(2)][hh(16)][f(8)][o(64)] (f==7 holds B1) = 16384 floats,
// then W2 image [hg(32)][o(64)] = 2048 floats. Total 18432 floats = 72 KB.
#define IMG_PER_I 18432

// ---------------------------------------------------------------------------
// Kernel 0: pre-swizzle W1/B1/W2 into the exact LDS image layout, one block
// per i. Reads coalesced, transposes through padded LDS (stride 225 / 33 ->
// 2-way bank aliasing, free), writes coalesced. Runs every call (~4.7 MB).
// ---------------------------------------------------------------------------
__global__ __launch_bounds__(256) void prep_kernel(const float* __restrict__ W1,
                                                   const float* __restrict__ W2,
                                                   const float* __restrict__ B1,
                                                   float* __restrict__ img) {
    __shared__ float l1[64 * 225];   // 57.6 KB (< 64 KB workgroup limit)
    const int i = blockIdx.x;
    const int tid = threadIdx.x;
    const float* W1i = W1 + i * (DOUT * NH * NF);   // 14336 floats, [o][h][f]
    for (int g = tid; g < 14336; g += 256) {
        int oo = g / 224;
        int r  = g % 224;
        l1[oo * 225 + r] = W1i[g];
    }
    __syncthreads();
    float* im = img + (size_t)i * IMG_PER_I;
    // img1: index ((ph*16+hh)*8+f)*64 + o ; f<7 from W1, f==7 from B1
    for (int g2 = tid; g2 < 16384; g2 += 256) {
        int o  = g2 & 63;
        int rr = g2 >> 6;        // 0..255 (wave-uniform)
        int f  = rr & 7;
        int hg = rr >> 3;        // 0..31
        float v = (f < 7) ? l1[o * 225 + hg * 7 + f]
                          : B1[i * 2048 + o * 32 + hg];
        im[g2] = v;
    }
    __syncthreads();
    // reuse l1 for the W2 transpose
    for (int g = tid; g < 2048; g += 256) {
        int oo = g >> 5, h = g & 31;
        l1[oo * 33 + h] = W2[i * 2048 + g];
    }
    __syncthreads();
    for (int g2 = tid; g2 < 2048; g2 += 256) {
        int o = g2 & 63, hg = g2 >> 6;
        im[16384 + g2] = l1[o * 33 + hg];
    }
}

// ---------------------------------------------------------------------------
// Kernel 1: features f[b,i,:] = [x, sin x, sin 2x, sin 4x, cos x, cos 2x, cos 4x]
// stored SoA feats[f][i][b] so main kernel reads 4 consecutive b per float4.
// ---------------------------------------------------------------------------
__global__ __launch_bounds__(256) void feats_kernel(const float* __restrict__ x,
                                                    float* __restrict__ feats) {
    int g = blockIdx.x * 256 + threadIdx.x;   // g = i*2048 + b
    int i = g >> 11;
    int b = g & 2047;
    float xv = x[b * DIN + i];
    float s1, c1;
    __sincosf(xv, &s1, &c1);
    float s2 = 2.0f * s1 * c1;
    float c2 = 1.0f - 2.0f * s1 * s1;
    float s4 = 2.0f * s2 * c2;
    float c4 = 1.0f - 2.0f * s2 * s2;
    feats[0 * NBI + g] = xv;
    feats[1 * NBI + g] = s1;
    feats[2 * NBI + g] = s2;
    feats[3 * NBI + g] = s4;
    feats[4 * NBI + g] = c1;
    feats[5 * NBI + g] = c2;
    feats[6 * NBI + g] = c4;
}

// ---------------------------------------------------------------------------
// Kernel 2: main compute. Block = 256 = 4 waves; lane = o. Staging is a pure
// contiguous copy from the prepped image (no address math, contiguous b128
// LDS writes). Compute LDS reads: plain [row][o] layout -> lane stride 4 B ->
// 2-way aliasing (free, m136) and single base VGPR + immediate offsets.
// 40 KB LDS -> 4 blocks/CU -> 16 waves/CU.
// ---------------------------------------------------------------------------
__global__ __launch_bounds__(256, 4) void main_kernel(
        const float* __restrict__ img, const float* __restrict__ B2,
        const float* __restrict__ feats, float* __restrict__ partials) {
    __shared__ float sW1[128 * 64];   // 32 KB: one ph half: [hh*8+f][o]
    __shared__ float sW2[32 * 64];    // 8 KB:  [hg][o]

    const int tid = threadIdx.x;
    const int o   = tid & 63;
    const int w   = tid >> 6;
    const int bchunk = blockIdx.x & 63;   // 64 chunks of 32 b
    const int ig     = blockIdx.x >> 6;   // 16 i-groups
    const int bbase  = bchunk * BCH + w * 8;

    float phi[8];
#pragma unroll
    for (int k = 0; k < 8; ++k) phi[k] = 0.0f;
    float b2s = 0.0f;

    for (int ii = 0; ii < IG; ++ii) {
        const int i = ig * IG + ii;
        const float* __restrict__ imi = img + (size_t)i * IMG_PER_I;
        b2s += B2[i * 64 + o];

        for (int ph = 0; ph < 2; ++ph) {
            __syncthreads();   // previous compute done before overwrite
            const float* __restrict__ src = imi + ph * 8192;
#pragma unroll
            for (int it = 0; it < 8; ++it) {
                int idx = it * 1024 + tid * 4;
                *(float4*)(sW1 + idx) = *(const float4*)(src + idx);
            }
            if (ph == 0) {
#pragma unroll
                for (int it = 0; it < 2; ++it) {
                    int idx = it * 1024 + tid * 4;
                    *(float4*)(sW2 + idx) = *(const float4*)(imi + 16384 + idx);
                }
            }
            __syncthreads();

            for (int t = 0; t < 2; ++t) {
                const int b0 = bbase + t * 4;
                // wave-uniform feature base -> scalar loads (s_load_dwordx4)
                const int fbase = __builtin_amdgcn_readfirstlane(i * 2048 + b0);
                float F[7][4];
#pragma unroll
                for (int j = 0; j < 7; ++j) {
                    float4 v = *(const float4*)(feats + j * NBI + fbase);
                    F[j][0] = v.x; F[j][1] = v.y; F[j][2] = v.z; F[j][3] = v.w;
                }
#pragma unroll 4
                for (int hh = 0; hh < 16; ++hh) {
                    float wv[7];
#pragma unroll
                    for (int j = 0; j < 7; ++j) wv[j] = sW1[(hh * 8 + j) * 64 + o];
                    const float b1v = sW1[(hh * 8 + 7) * 64 + o];
                    const float w2h = sW2[(ph * 16 + hh) * 64 + o];
#pragma unroll
                    for (int k = 0; k < 4; ++k) {
                        float a = b1v;
#pragma unroll
                        for (int j = 0; j < 7; ++j) a = __builtin_fmaf(wv[j], F[j][k], a);
                        // silu(a) = a / (1 + e^-a): v_exp + v_add + v_rcp + v_mul
                        float e = __expf(-a);
                        float s = a * __builtin_amdgcn_rcpf(1.0f + e);
                        phi[t * 4 + k] = __builtin_fmaf(s, w2h, phi[t * 4 + k]);
                    }
                }
            }
        }
    }

    // write partials[ig][b][o], coalesced over o; fold B2 sum in once
    float* pp = partials + ig * (B_SZ * DOUT);
#pragma unroll
    for (int k = 0; k < 8; ++k) {
        pp[(bbase + k) * 64 + o] = phi[k] + b2s;
    }
}

// ---------------------------------------------------------------------------
// Kernel 3: reduce the 16 i-group partials -> out[b][o]
// ---------------------------------------------------------------------------
__global__ __launch_bounds__(256) void reduce_kernel(const float* __restrict__ partials,
                                                     float* __restrict__ out) {
    int t = blockIdx.x * 256 + threadIdx.x;   // < 131072
    float s = 0.0f;
#pragma unroll
    for (int g = 0; g < NGRP; ++g) s += partials[g * (B_SZ * DOUT) + t];
    out[t] = s;
}

extern "C" void kernel_launch(void* const* d_in, const int* in_sizes, int n_in,
                              void* d_out, int out_size, void* d_ws, size_t ws_size,
                              hipStream_t stream) {
    const float* x  = (const float*)d_in[0];
    const float* W1 = (const float*)d_in[1];
    const float* W2 = (const float*)d_in[2];
    const float* B1 = (const float*)d_in[3];
    const float* B2 = (const float*)d_in[4];
    float* out = (float*)d_out;

    // ws layout (floats): feats [7*131072] | partials [16*131072] | img [64*18432]
    float* feats    = (float*)d_ws;
    float* partials = feats + (size_t)NF * NBI;
    float* img      = partials + (size_t)NGRP * B_SZ * DOUT;
    // total = 3.67 MB + 8.39 MB + 4.72 MB ≈ 16.8 MB

    prep_kernel<<<DIN, 256, 0, stream>>>(W1, W2, B1, img);
    feats_kernel<<<NBI / 256, 256, 0, stream>>>(x, feats);
    main_kernel<<<NGRP * (B_SZ / BCH), 256, 0, stream>>>(img, B2, feats, partials);
    reduce_kernel<<<(B_SZ * DOUT) / 256, 256, 0, stream>>>(partials, out);
}

// Round 3
// 177.362 us; speedup vs baseline: 1.8778x; 1.0096x over previous
//
#include <hip/hip_runtime.h>
#include <math.h>

typedef _Float16 f16;
typedef f16  f16x8  __attribute__((ext_vector_type(8)));
typedef float floatx4 __attribute__((ext_vector_type(4)));

// Problem constants
#define B_SZ  2048
#define DIN   64
#define DOUT  64
#define NH    32
#define NBT   128               // b-tiles of 16
#define IG    8                 // i's per block
#define NGRP  (DIN / IG)        // 8 partial groups

// f16 images (built by prep_kernel):
//  w1img: A-operand quads-0 data. [i][o][half][c(16)][j(8)]; c = h within half,
//         j = f (j==7 holds B1).  idx = (((i*64+o)*2+half)*16 + c)*8
//  fimg : B-operand quads-0 data. [i][btile][c(16)][j(8)]; c = b within tile,
//         j = f (j==7 == 1.0 bias feature). idx = ((i*128+bt)*16 + c)*8
#define W1IMG_ELEMS (64 * 64 * 2 * 16 * 8)   // 1,048,576 f16 = 2 MB
#define FIMG_ELEMS  (64 * 128 * 16 * 8)      // 1,048,576 f16 = 2 MB

// ---------------------------------------------------------------------------
// prep: blocks 0..511 build w1img, 512..1023 build fimg, block 1024 does B2sum
// ---------------------------------------------------------------------------
__global__ __launch_bounds__(256) void prep_kernel(
        const float* __restrict__ W1, const float* __restrict__ B1,
        const float* __restrict__ B2, const float* __restrict__ x,
        f16* __restrict__ w1img, f16* __restrict__ fimg,
        float* __restrict__ b2sum) {
    const int bid = blockIdx.x;
    const int tid = threadIdx.x;
    if (bid < 512) {
        int g = bid * 256 + tid;            // g = i*2048 + o*32 + half*16 + c
        int c = g & 15, half = (g >> 4) & 1, o = (g >> 5) & 63, i = g >> 11;
        int h = half * 16 + c;
        const float* w = W1 + ((i * 64 + o) * 32 + h) * 7;
        f16x8 v;
#pragma unroll
        for (int j = 0; j < 7; ++j) v[j] = (f16)w[j];
        v[7] = (f16)B1[(i * 64 + o) * 32 + h];
        *(f16x8*)(w1img + (size_t)g * 8) = v;
    } else if (bid < 1024) {
        int g = (bid - 512) * 256 + tid;    // g = i*2048 + bt*16 + c
        int c = g & 15, bt = (g >> 4) & 127, i = g >> 11;
        int b = bt * 16 + c;
        float xv = x[b * 64 + i];
        float s1, c1;
        __sincosf(xv, &s1, &c1);
        float s2 = 2.0f * s1 * c1, c2 = 1.0f - 2.0f * s1 * s1;
        float s4 = 2.0f * s2 * c2, c4 = 1.0f - 2.0f * s2 * s2;
        f16x8 v;
        v[0] = (f16)xv; v[1] = (f16)s1; v[2] = (f16)s2; v[3] = (f16)s4;
        v[4] = (f16)c1; v[5] = (f16)c2; v[6] = (f16)c4; v[7] = (f16)1.0f;
        *(f16x8*)(fimg + (size_t)g * 8) = v;
    } else if (tid < 64) {
        float s = 0.0f;
        for (int i = 0; i < 64; ++i) s += B2[i * 64 + tid];
        b2sum[tid] = s;
    }
}

// ---------------------------------------------------------------------------
// main: block = 4 waves; wave oq owns o-quarter, all waves share one b-16-tile.
// Per (i, o, half): C[h(16) x b(16)] = mfma16x16x32_f16(W1frag, Ffrag, 0)
// (k = 8 real: 7 feats + bias; quads 1..3 of both operands are zero and never
//  loaded). silu in-register, scale by w2[h] (float4/lane), accumulate
// phi[o'] per-lane (b = col). h-quad reduction via 2-step shfl_xor. No LDS.
// ---------------------------------------------------------------------------
__global__ __launch_bounds__(256, 4) void main_kernel(
        const f16* __restrict__ w1img, const f16* __restrict__ fimg,
        const float* __restrict__ W2, float* __restrict__ partials) {
    const int tid   = threadIdx.x;
    const int lane  = tid & 63;
    const int oq    = tid >> 6;          // wave's o-quarter
    const int g     = lane >> 4;         // quad
    const int c     = lane & 15;
    const int btile = blockIdx.x & 127;
    const int ig    = blockIdx.x >> 7;

    float phi[16];
#pragma unroll
    for (int e = 0; e < 16; ++e) phi[e] = 0.0f;

    for (int ii = 0; ii < IG; ++ii) {
        const int i = ig * IG + ii;
        // B-operand (features of this b-tile): quad 0 only, held all i-iter
        f16x8 bfrag = {};
        if (g == 0)
            bfrag = *(const f16x8*)(fimg + (size_t)((i * 128 + btile) * 16 + c) * 8);

#pragma unroll 2
        for (int op = 0; op < 16; ++op) {
            const int o = oq * 16 + op;
#pragma unroll
            for (int half = 0; half < 2; ++half) {
                f16x8 afrag = {};
                if (g == 0)
                    afrag = *(const f16x8*)(w1img +
                        (size_t)(((i * 64 + o) * 2 + half) * 16 + c) * 8);
                floatx4 C = __builtin_amdgcn_mfma_f32_16x16x32_f16(
                    afrag, bfrag, (floatx4){0.0f, 0.0f, 0.0f, 0.0f}, 0, 0, 0);
                // w2 for rows h = half*16 + g*4 + r  (16B aligned)
                const floatx4 w2v =
                    *(const floatx4*)(W2 + ((i * 64 + o) * 32 + half * 16 + g * 4));
#pragma unroll
                for (int r = 0; r < 4; ++r) {
                    float a = C[r];
                    float e = __expf(-a);
                    float s = a * __builtin_amdgcn_rcpf(1.0f + e);
                    phi[op] = __builtin_fmaf(s, w2v[r], phi[op]);
                }
            }
        }
    }

    // sum the 4 h-quads (lanes differ only in g for fixed c)
#pragma unroll
    for (int e = 0; e < 16; ++e) {
        phi[e] += __shfl_xor(phi[e], 16, 64);
        phi[e] += __shfl_xor(phi[e], 32, 64);
    }

    // lane (g,c): b = btile*16 + c, writes o' = 4g..4g+3 (static selects)
    float* pp = partials + (size_t)ig * (B_SZ * DOUT) +
                (btile * 16 + c) * 64 + oq * 16 + g * 4;
#pragma unroll
    for (int k = 0; k < 4; ++k) {
        float v0 = (g < 2) ? ((g == 0) ? phi[k] : phi[4 + k])
                           : ((g == 2) ? phi[8 + k] : phi[12 + k]);
        pp[k] = v0;
    }
}

// ---------------------------------------------------------------------------
// reduce: out[b,o] = sum_g partials + B2sum[o]
// ---------------------------------------------------------------------------
__global__ __launch_bounds__(256) void reduce_kernel(
        const float* __restrict__ partials, const float* __restrict__ b2sum,
        float* __restrict__ out) {
    int t = blockIdx.x * 256 + threadIdx.x;   // < 131072
    float s = b2sum[t & 63];
#pragma unroll
    for (int gg = 0; gg < NGRP; ++gg) s += partials[(size_t)gg * (B_SZ * DOUT) + t];
    out[t] = s;
}

extern "C" void kernel_launch(void* const* d_in, const int* in_sizes, int n_in,
                              void* d_out, int out_size, void* d_ws, size_t ws_size,
                              hipStream_t stream) {
    const float* x  = (const float*)d_in[0];
    const float* W1 = (const float*)d_in[1];
    const float* W2 = (const float*)d_in[2];
    const float* B1 = (const float*)d_in[3];
    const float* B2 = (const float*)d_in[4];
    float* out = (float*)d_out;

    // ws layout: w1img (2MB f16) | fimg (2MB f16) | b2sum (64 f32) | partials (4MB f32)
    f16*   w1img    = (f16*)d_ws;
    f16*   fimg     = w1img + W1IMG_ELEMS;
    float* b2sum    = (float*)(fimg + FIMG_ELEMS);
    float* partials = b2sum + 64;

    prep_kernel<<<1025, 256, 0, stream>>>(W1, B1, B2, x, w1img, fimg, b2sum);
    main_kernel<<<NGRP * NBT, 256, 0, stream>>>(w1img, fimg, W2, partials);
    reduce_kernel<<<(B_SZ * DOUT) / 256, 256, 0, stream>>>(partials, b2sum, out);
}

// Round 4
// 158.704 us; speedup vs baseline: 2.0986x; 1.1176x over previous
//
#include <hip/hip_runtime.h>
#include <math.h>

typedef _Float16 f16;
typedef f16  f16x8  __attribute__((ext_vector_type(8)));
typedef float floatx4 __attribute__((ext_vector_type(4)));

#define LOG2E 1.44269504088896340736f

// Problem constants
#define B_SZ  2048
#define DIN   64
#define DOUT  64
#define NH    32

// w1img: f16, layout [i][o][half][lane(64)][j(8)]; lane quads 1..3 are ZERO,
//        quad0 lane c holds A[m=h=half*16+c][k=j] = W1[i,o,h,j]*(-LOG2E),
//        j==7 holds B1[i,o,h]*(-LOG2E). Total 64*64*2*64*8 f16 = 8 MB.
// w2img: f32, original [i][o][h] order, scaled by (-1/LOG2E). 512 KB.
#define W1IMG_ELEMS ((size_t)DIN * DOUT * 2 * 64 * 8)

// ---------------------------------------------------------------------------
// prep: blocks 0..2047 build w1img (one 16B fragment-lane entry per thread,
// coalesced writes); blocks 2048..2559 scale W2 -> w2img.
// ---------------------------------------------------------------------------
__global__ __launch_bounds__(256) void prep_kernel(
        const float* __restrict__ W1, const float* __restrict__ B1,
        const float* __restrict__ W2,
        f16* __restrict__ w1img, float* __restrict__ w2img) {
    const int bid = blockIdx.x, tid = threadIdx.x;
    if (bid < 2048) {
        int e    = bid * 256 + tid;          // [i][o][half][lane]
        int lane = e & 63;
        int half = (e >> 6) & 1;
        int o    = (e >> 7) & 63;
        int i    = e >> 13;
        f16x8 v = {};
        if ((lane >> 4) == 0) {
            int h = half * 16 + (lane & 15);
            const float* w = W1 + (size_t)((i * 64 + o) * 32 + h) * 7;
#pragma unroll
            for (int j = 0; j < 7; ++j) v[j] = (f16)(w[j] * (-LOG2E));
            v[7] = (f16)(B1[(i * 64 + o) * 32 + h] * (-LOG2E));
        }
        *(f16x8*)(w1img + (size_t)e * 8) = v;
    } else {
        int e = (bid - 2048) * 256 + tid;    // < 131072
        w2img[e] = W2[e] * (-1.0f / LOG2E);
    }
}

// ---------------------------------------------------------------------------
// main: grid = 64 btile-pairs x 16 o-groups; block = 4 waves, wave w owns
// o = og*4+w. Stage features for the block's 32 b's x 64 i into LDS (f16x8,
// bias feature = 1.0), one barrier. i-loop 0..63 software-pipelined:
// unconditional coalesced afrag loads (zeros live in w1img), broadcast
// ds_read_b128 bfrag, per-(i,half) float4 w2. 4 MFMAs/iter, silu =
// exp2+add+rcp+mul+fma. phi accumulated over all i -> h-quad shfl reduce ->
// direct out write (+B2 column sum via wave-uniform loads). No partials.
// ---------------------------------------------------------------------------
__global__ __launch_bounds__(256, 4) void main_kernel(
        const f16* __restrict__ w1img, const float* __restrict__ w2img,
        const float* __restrict__ B2, const float* __restrict__ x,
        float* __restrict__ out) {
    __shared__ f16 feats[65 * 33 * 8];   // [i][bb] pad 33; +1 i-row for prefetch overrun

    const int tid = threadIdx.x;
    const int btp = blockIdx.x & 63;     // b-base = btp*32
    const int og  = blockIdx.x >> 6;

    // ---- stage features: thread covers (i = p*8 + (tid>>5), bb = tid&31)
    {
        const int bb = tid & 31, isub = tid >> 5;
        const int b  = btp * 32 + bb;
#pragma unroll
        for (int p = 0; p < 8; ++p) {
            const int i = p * 8 + isub;
            float xv = x[b * 64 + i];
            float s1, c1;
            __sincosf(xv, &s1, &c1);
            float s2 = 2.0f * s1 * c1, c2 = 1.0f - 2.0f * s1 * s1;
            float s4 = 2.0f * s2 * c2, c4 = 1.0f - 2.0f * s2 * s2;
            f16x8 v;
            v[0] = (f16)xv; v[1] = (f16)s1; v[2] = (f16)s2; v[3] = (f16)s4;
            v[4] = (f16)c1; v[5] = (f16)c2; v[6] = (f16)c4; v[7] = (f16)1.0f;
            *(f16x8*)(feats + (i * 33 + bb) * 8) = v;
        }
    }
    __syncthreads();

    const int lane = tid & 63;
    const int w    = tid >> 6;
    const int o    = __builtin_amdgcn_readfirstlane(og * 4 + w);
    const int g    = lane >> 4, c = lane & 15;

    // per-wave base pointers (i-stride added in-loop)
    const f16*   w1p = w1img + ((size_t)o * 128 + lane) * 8;  // +i*65536, +half*512
    const float* w2p = w2img + o * 32 + g * 4;                // +i*2048, +half*16
    const f16*   fb  = feats + c * 8;                         // +i*264, +bt*128

    float phi0 = 0.0f, phi1 = 0.0f, b2s = 0.0f;

    // prefetch i = 0
    f16x8  a0 = *(const f16x8*)(w1p);
    f16x8  a1 = *(const f16x8*)(w1p + 512);
    f16x8  b0 = *(const f16x8*)(fb);
    f16x8  b1 = *(const f16x8*)(fb + 128);
    floatx4 w20 = *(const floatx4*)(w2p);
    floatx4 w21 = *(const floatx4*)(w2p + 16);

#pragma unroll 4
    for (int i = 0; i < 64; ++i) {
        const f16x8  ca0 = a0, ca1 = a1, cb0 = b0, cb1 = b1;
        const floatx4 cw0 = w20, cw1 = w21;

        // prefetch i+1 (i==63 reads one row past: ws/LDS padded, values unused)
        {
            const size_t i1 = (size_t)(i + 1);
            a0  = *(const f16x8*)(w1p + i1 * 65536);
            a1  = *(const f16x8*)(w1p + i1 * 65536 + 512);
            b0  = *(const f16x8*)(fb + i1 * 264);
            b1  = *(const f16x8*)(fb + i1 * 264 + 128);
            w20 = *(const floatx4*)(w2p + i1 * 2048);
            w21 = *(const floatx4*)(w2p + i1 * 2048 + 16);
        }

        b2s += B2[(size_t)i * 64 + o];   // wave-uniform -> scalar load

        floatx4 C00 = __builtin_amdgcn_mfma_f32_16x16x32_f16(
            ca0, cb0, (floatx4){0.f, 0.f, 0.f, 0.f}, 0, 0, 0);  // half0, bt0
        floatx4 C01 = __builtin_amdgcn_mfma_f32_16x16x32_f16(
            ca0, cb1, (floatx4){0.f, 0.f, 0.f, 0.f}, 0, 0, 0);  // half0, bt1
        floatx4 C10 = __builtin_amdgcn_mfma_f32_16x16x32_f16(
            ca1, cb0, (floatx4){0.f, 0.f, 0.f, 0.f}, 0, 0, 0);  // half1, bt0
        floatx4 C11 = __builtin_amdgcn_mfma_f32_16x16x32_f16(
            ca1, cb1, (floatx4){0.f, 0.f, 0.f, 0.f}, 0, 0, 0);  // half1, bt1

        // silu * w2: a'' = -log2e * a was produced by the scaled weights;
        // sigma = rcp(1 + 2^{a''}); contribution = a''*sigma*w2'' (w2'' = -w2/log2e)
#pragma unroll
        for (int r = 0; r < 4; ++r) {
            float av, e2, sg;
            av = C00[r]; e2 = __builtin_amdgcn_exp2f(av);
            sg = __builtin_amdgcn_rcpf(1.0f + e2);
            phi0 = __builtin_fmaf(av * cw0[r], sg, phi0);
            av = C01[r]; e2 = __builtin_amdgcn_exp2f(av);
            sg = __builtin_amdgcn_rcpf(1.0f + e2);
            phi1 = __builtin_fmaf(av * cw0[r], sg, phi1);
            av = C10[r]; e2 = __builtin_amdgcn_exp2f(av);
            sg = __builtin_amdgcn_rcpf(1.0f + e2);
            phi0 = __builtin_fmaf(av * cw1[r], sg, phi0);
            av = C11[r]; e2 = __builtin_amdgcn_exp2f(av);
            sg = __builtin_amdgcn_rcpf(1.0f + e2);
            phi1 = __builtin_fmaf(av * cw1[r], sg, phi1);
        }
    }

    // reduce over the 4 h-quads (lanes differ only in g for fixed c)
    phi0 += __shfl_xor(phi0, 16, 64);
    phi0 += __shfl_xor(phi0, 32, 64);
    phi1 += __shfl_xor(phi1, 16, 64);
    phi1 += __shfl_xor(phi1, 32, 64);

    if (g == 0) {
        out[(btp * 32 + c) * 64 + o]      = phi0 + b2s;
        out[(btp * 32 + 16 + c) * 64 + o] = phi1 + b2s;
    }
}

extern "C" void kernel_launch(void* const* d_in, const int* in_sizes, int n_in,
                              void* d_out, int out_size, void* d_ws, size_t ws_size,
                              hipStream_t stream) {
    const float* x  = (const float*)d_in[0];
    const float* W1 = (const float*)d_in[1];
    const float* W2 = (const float*)d_in[2];
    const float* B1 = (const float*)d_in[3];
    const float* B2 = (const float*)d_in[4];
    float* out = (float*)d_out;

    // ws: w1img (8 MB f16) | w2img (512 KB f32) | slack for prefetch overrun
    f16*   w1img = (f16*)d_ws;
    float* w2img = (float*)(w1img + W1IMG_ELEMS);

    prep_kernel<<<2560, 256, 0, stream>>>(W1, B1, W2, w1img, w2img);
    main_kernel<<<64 * 16, 256, 0, stream>>>(w1img, w2img, B2, x, out);
}

// Round 5
// 142.079 us; speedup vs baseline: 2.3441x; 1.1170x over previous
//
#include <hip/hip_runtime.h>
#include <math.h>

typedef _Float16 f16;
typedef f16   f16x8   __attribute__((ext_vector_type(8)));
typedef float floatx4 __attribute__((ext_vector_type(4)));
typedef float floatx16 __attribute__((ext_vector_type(16)));

#define LOG2E 1.44269504088896340736f

// Problem constants
#define B_SZ  2048
#define DIN   64
#define DOUT  64
#define NH    32

// Images (built by prep_kernel):
//  w1img f16 [i][o][lane(64)][j(8)]: A-frag for mfma_32x32x16, m=h=lane&31,
//        k=(lane>>5)*8+j. lanes 32..63 (k=8..15) are ZERO. Values scaled by
//        -log2e; j==7 holds B1*(-log2e) (bias via the constant-1 feature).
//  fimg  f16 [i][btp(64)][lane(64)][j(8)]: B-frag, n=b=lane&31, k as above;
//        j==7 = 1.0 (bias feature); lanes 32..63 ZERO.
//  w2q   f32 [i][o][q(4)][p(2)][r(4)] = W2[i,o,h=q*8+p*4+r] * (-1/log2e)
//        -> lane (p=lane>>5) reads its 16 C-row w2 values as 4 float4s.
//  b2sum f32 [64]: column sums of B2.
#define W1IMG_ELEMS ((size_t)DIN * DOUT * 64 * 8)   // 2,097,152 f16 = 4 MB
#define FIMG_ELEMS  ((size_t)DIN * 64 * 64 * 8)     // 2,097,152 f16 = 4 MB
#define W2Q_ELEMS   ((size_t)DIN * DOUT * NH)       // 131,072 f32 = 512 KB

// ---------------------------------------------------------------------------
// prep: bid 0..1023 -> w1img, 1024..2047 -> fimg, 2048..2559 -> w2q,
//       2560 -> b2sum. All writes coalesced 16B (or 4B).
// ---------------------------------------------------------------------------
__global__ __launch_bounds__(256) void prep_kernel(
        const float* __restrict__ W1, const float* __restrict__ B1,
        const float* __restrict__ W2, const float* __restrict__ B2,
        const float* __restrict__ x,
        f16* __restrict__ w1img, f16* __restrict__ fimg,
        float* __restrict__ w2q, float* __restrict__ b2sum) {
    const int bid = blockIdx.x, tid = threadIdx.x;
    if (bid < 1024) {
        int e = bid * 256 + tid;             // [i][o][lane]
        int lane = e & 63, o = (e >> 6) & 63, i = e >> 12;
        f16x8 v = {};
        if (lane < 32) {
            const float* w = W1 + (size_t)((i * 64 + o) * 32 + lane) * 7;
#pragma unroll
            for (int j = 0; j < 7; ++j) v[j] = (f16)(w[j] * (-LOG2E));
            v[7] = (f16)(B1[(i * 64 + o) * 32 + lane] * (-LOG2E));
        }
        *(f16x8*)(w1img + (size_t)e * 8) = v;
    } else if (bid < 2048) {
        int e = (bid - 1024) * 256 + tid;    // [i][btp][lane]
        int lane = e & 63, btp = (e >> 6) & 63, i = e >> 12;
        f16x8 v = {};
        if (lane < 32) {
            int b = btp * 32 + lane;
            float xv = x[b * 64 + i];
            float s1, c1;
            __sincosf(xv, &s1, &c1);
            float s2 = 2.0f * s1 * c1, c2 = 1.0f - 2.0f * s1 * s1;
            float s4 = 2.0f * s2 * c2, c4 = 1.0f - 2.0f * s2 * s2;
            v[0] = (f16)xv; v[1] = (f16)s1; v[2] = (f16)s2; v[3] = (f16)s4;
            v[4] = (f16)c1; v[5] = (f16)c2; v[6] = (f16)c4; v[7] = (f16)1.0f;
        }
        *(f16x8*)(fimg + (size_t)e * 8) = v;
    } else if (bid < 2560) {
        int e = (bid - 2048) * 256 + tid;    // < 131072
        int r = e & 3, p = (e >> 2) & 1, q = (e >> 3) & 3;
        int o = (e >> 5) & 63, i = e >> 11;
        int h = q * 8 + p * 4 + r;
        w2q[e] = W2[(size_t)(i * 64 + o) * 32 + h] * (-1.0f / LOG2E);
    } else if (tid < 64) {
        float s = 0.0f;
        for (int i = 0; i < 64; ++i) s += B2[i * 64 + tid];
        b2sum[tid] = s;
    }
}

// ---------------------------------------------------------------------------
// main: grid = 64 btp x 32 og, block = 128 (2 waves); wave w -> o = og*2+w.
// Per i: ONE mfma_32x32x16 gives C[h(32) x b(32)] for this o (K=16, real k=8,
// zeros baked into the images -> all loads unconditional). silu in-register
// (weights pre-scaled by -log2e: sg = rcp(1+2^a''), phi += a''*w2''*sg),
// phi = 1 reg/lane (lane owns col b), software-pipelined 1 iter ahead.
// No LDS, no barriers, no partials: shfl_xor(32) + direct out write.
// ---------------------------------------------------------------------------
__global__ __launch_bounds__(128, 4) void main_kernel(
        const f16* __restrict__ w1img, const f16* __restrict__ fimg,
        const float* __restrict__ w2q, const float* __restrict__ b2sum,
        float* __restrict__ out) {
    const int tid  = threadIdx.x;
    const int lane = tid & 63;
    const int wv   = tid >> 6;
    const int btp  = blockIdx.x & 63;
    const int og   = blockIdx.x >> 6;
    const int o    = __builtin_amdgcn_readfirstlane(og * 2 + wv);
    const int p    = lane >> 5;

    const f16*   ap = w1img + ((size_t)o * 64 + lane) * 8;    // + i*32768
    const f16*   bp = fimg + ((size_t)btp * 64 + lane) * 8;   // + i*32768
    const float* wp = w2q + (size_t)o * 32 + p * 4;           // + i*2048

    // prefetch i = 0
    f16x8 a = *(const f16x8*)ap;
    f16x8 b = *(const f16x8*)bp;
    floatx4 w0 = *(const floatx4*)(wp);
    floatx4 w1 = *(const floatx4*)(wp + 8);
    floatx4 w2 = *(const floatx4*)(wp + 16);
    floatx4 w3 = *(const floatx4*)(wp + 24);

    float phi = 0.0f;
    const floatx16 zeroC = {};

#pragma unroll 1
    for (int i = 0; i < 64; ++i) {
        const f16x8 ca = a, cb = b;
        const floatx4 cw0 = w0, cw1 = w1, cw2 = w2, cw3 = w3;

        // prefetch i+1 (i==63 overruns into the adjacent ws arrays/pad —
        // values never consumed)
        const size_t i1 = (size_t)(i + 1);
        a  = *(const f16x8*)(ap + i1 * 32768);
        b  = *(const f16x8*)(bp + i1 * 32768);
        w0 = *(const floatx4*)(wp + i1 * 2048);
        w1 = *(const floatx4*)(wp + i1 * 2048 + 8);
        w2 = *(const floatx4*)(wp + i1 * 2048 + 16);
        w3 = *(const floatx4*)(wp + i1 * 2048 + 24);

        floatx16 C = __builtin_amdgcn_mfma_f32_32x32x16_f16(ca, cb, zeroC, 0, 0, 0);

#pragma unroll
        for (int r = 0; r < 4; ++r) {
            float av, e2, sg;
            av = C[0 + r];  e2 = __builtin_amdgcn_exp2f(av);
            sg = __builtin_amdgcn_rcpf(1.0f + e2);
            phi = __builtin_fmaf(av * cw0[r], sg, phi);
            av = C[4 + r];  e2 = __builtin_amdgcn_exp2f(av);
            sg = __builtin_amdgcn_rcpf(1.0f + e2);
            phi = __builtin_fmaf(av * cw1[r], sg, phi);
            av = C[8 + r];  e2 = __builtin_amdgcn_exp2f(av);
            sg = __builtin_amdgcn_rcpf(1.0f + e2);
            phi = __builtin_fmaf(av * cw2[r], sg, phi);
            av = C[12 + r]; e2 = __builtin_amdgcn_exp2f(av);
            sg = __builtin_amdgcn_rcpf(1.0f + e2);
            phi = __builtin_fmaf(av * cw3[r], sg, phi);
        }
    }

    // combine the two row-halves (lane and lane^32 share the same column)
    phi += __shfl_xor(phi, 32, 64);

    if (lane < 32) {
        out[(size_t)(btp * 32 + lane) * 64 + o] = phi + b2sum[o];
    }
}

extern "C" void kernel_launch(void* const* d_in, const int* in_sizes, int n_in,
                              void* d_out, int out_size, void* d_ws, size_t ws_size,
                              hipStream_t stream) {
    const float* x  = (const float*)d_in[0];
    const float* W1 = (const float*)d_in[1];
    const float* W2 = (const float*)d_in[2];
    const float* B1 = (const float*)d_in[3];
    const float* B2 = (const float*)d_in[4];
    float* out = (float*)d_out;

    // ws: w1img (4MB) | fimg (4MB) | w2q (512KB) | b2sum (256B) | pad
    f16*   w1img = (f16*)d_ws;
    f16*   fimg  = w1img + W1IMG_ELEMS;
    float* w2q   = (float*)(fimg + FIMG_ELEMS);
    float* b2sum = w2q + W2Q_ELEMS;

    prep_kernel<<<2561, 256, 0, stream>>>(W1, B1, W2, B2, x, w1img, fimg, w2q, b2sum);
    main_kernel<<<64 * 32, 128, 0, stream>>>(w1img, fimg, w2q, b2sum, out);
}

// Round 6
// 128.885 us; speedup vs baseline: 2.5841x; 1.1024x over previous
//
#include <hip/hip_runtime.h>
#include <math.h>

typedef _Float16 f16;
typedef f16   f16x8    __attribute__((ext_vector_type(8)));
typedef float floatx4  __attribute__((ext_vector_type(4)));
typedef float floatx16 __attribute__((ext_vector_type(16)));

#define LOG2E 1.44269504088896340736f

// Problem constants
#define B_SZ  2048
#define DIN   64
#define DOUT  64
#define NH    32

#define NIG   4                 // i-groups (occupancy: 8192 blocks)
#define IGW   (DIN / NIG)       // 16 i per block

// Images (built by prep_kernel):
//  w1img f16 [i][o][lane(64)][j(8)]: A-frag for mfma_32x32x16, m=h=lane&31,
//        k=(lane>>5)*8+j. lanes 32..63 (k=8..15) are ZERO. Values scaled by
//        -log2e; j==7 holds B1*(-log2e) (bias via the constant-1 feature).
//  fimg  f16 [i][btp(64)][lane(64)][j(8)]: B-frag, n=b=lane&31, k as above;
//        j==7 = 1.0 (bias feature); lanes 32..63 ZERO.
//  w2q   f32 [i][o][q(4)][p(2)][r(4)] = W2[i,o,h=q*8+p*4+r] * (-1/log2e)
//  b2sum f32 [64]: column sums of B2.
#define W1IMG_ELEMS ((size_t)DIN * DOUT * 64 * 8)   // 2,097,152 f16 = 4 MB
#define FIMG_ELEMS  ((size_t)DIN * 64 * 64 * 8)     // 2,097,152 f16 = 4 MB
#define W2Q_ELEMS   ((size_t)DIN * DOUT * NH)       // 131,072 f32 = 512 KB

// ---------------------------------------------------------------------------
// prep: bid 0..1023 -> w1img, 1024..2047 -> fimg, 2048..2559 -> w2q,
//       2560 -> b2sum. All writes coalesced 16B (or 4B).
// ---------------------------------------------------------------------------
__global__ __launch_bounds__(256) void prep_kernel(
        const float* __restrict__ W1, const float* __restrict__ B1,
        const float* __restrict__ W2, const float* __restrict__ B2,
        const float* __restrict__ x,
        f16* __restrict__ w1img, f16* __restrict__ fimg,
        float* __restrict__ w2q, float* __restrict__ b2sum) {
    const int bid = blockIdx.x, tid = threadIdx.x;
    if (bid < 1024) {
        int e = bid * 256 + tid;             // [i][o][lane]
        int lane = e & 63, o = (e >> 6) & 63, i = e >> 12;
        f16x8 v = {};
        if (lane < 32) {
            const float* w = W1 + (size_t)((i * 64 + o) * 32 + lane) * 7;
#pragma unroll
            for (int j = 0; j < 7; ++j) v[j] = (f16)(w[j] * (-LOG2E));
            v[7] = (f16)(B1[(i * 64 + o) * 32 + lane] * (-LOG2E));
        }
        *(f16x8*)(w1img + (size_t)e * 8) = v;
    } else if (bid < 2048) {
        int e = (bid - 1024) * 256 + tid;    // [i][btp][lane]
        int lane = e & 63, btp = (e >> 6) & 63, i = e >> 12;
        f16x8 v = {};
        if (lane < 32) {
            int b = btp * 32 + lane;
            float xv = x[b * 64 + i];
            float s1, c1;
            __sincosf(xv, &s1, &c1);
            float s2 = 2.0f * s1 * c1, c2 = 1.0f - 2.0f * s1 * s1;
            float s4 = 2.0f * s2 * c2, c4 = 1.0f - 2.0f * s2 * s2;
            v[0] = (f16)xv; v[1] = (f16)s1; v[2] = (f16)s2; v[3] = (f16)s4;
            v[4] = (f16)c1; v[5] = (f16)c2; v[6] = (f16)c4; v[7] = (f16)1.0f;
        }
        *(f16x8*)(fimg + (size_t)e * 8) = v;
    } else if (bid < 2560) {
        int e = (bid - 2048) * 256 + tid;    // < 131072
        int r = e & 3, p = (e >> 2) & 1, q = (e >> 3) & 3;
        int o = (e >> 5) & 63, i = e >> 11;
        int h = q * 8 + p * 4 + r;
        w2q[e] = W2[(size_t)(i * 64 + o) * 32 + h] * (-1.0f / LOG2E);
    } else if (tid < 64) {
        float s = 0.0f;
        for (int i = 0; i < 64; ++i) s += B2[i * 64 + tid];
        b2sum[tid] = s;
    }
}

// ---------------------------------------------------------------------------
// main: grid = 4 ig x 32 og x 64 btp = 8192 blocks, block = 128 (2 waves);
// wave w -> o = og*2+w, i in [ig*16, ig*16+16). Per i: ONE mfma_32x32x16
// gives C[h(32) x b(32)] (real K=8, zeros baked into images -> all loads
// unconditional). silu in-register (weights pre-scaled by -log2e:
// sg = rcp(1+2^a''), phi += a''*w2''*sg), 1 phi reg/lane, pipelined 1 ahead.
// No LDS/barriers; partial plane per ig, reduced by reduce_kernel.
// ---------------------------------------------------------------------------
__global__ __launch_bounds__(128, 4) void main_kernel(
        const f16* __restrict__ w1img, const f16* __restrict__ fimg,
        const float* __restrict__ w2q, float* __restrict__ partials) {
    const int tid  = threadIdx.x;
    const int lane = tid & 63;
    const int wv   = tid >> 6;
    const int btp  = blockIdx.x & 63;
    const int og   = (blockIdx.x >> 6) & 31;
    const int ig   = blockIdx.x >> 11;
    const int o    = __builtin_amdgcn_readfirstlane(og * 2 + wv);
    const int p    = lane >> 5;

    const size_t ibase = (size_t)ig * IGW;
    const f16*   ap = w1img + ibase * 32768 + ((size_t)o * 64 + lane) * 8;
    const f16*   bp = fimg  + ibase * 32768 + ((size_t)btp * 64 + lane) * 8;
    const float* wp = w2q   + ibase * 2048  + (size_t)o * 32 + p * 4;

    // prefetch ii = 0
    f16x8 a = *(const f16x8*)ap;
    f16x8 b = *(const f16x8*)bp;
    floatx4 w0 = *(const floatx4*)(wp);
    floatx4 w1 = *(const floatx4*)(wp + 8);
    floatx4 w2 = *(const floatx4*)(wp + 16);
    floatx4 w3 = *(const floatx4*)(wp + 24);

    float phi = 0.0f;
    const floatx16 zeroC = {};

#pragma unroll 1
    for (int ii = 0; ii < IGW; ++ii) {
        const f16x8 ca = a, cb = b;
        const floatx4 cw0 = w0, cw1 = w1, cw2 = w2, cw3 = w3;

        // prefetch ii+1 (last iter overruns into adjacent ws regions — values
        // loaded but never consumed; ws has pad at the end)
        const size_t i1 = (size_t)(ii + 1);
        a  = *(const f16x8*)(ap + i1 * 32768);
        b  = *(const f16x8*)(bp + i1 * 32768);
        w0 = *(const floatx4*)(wp + i1 * 2048);
        w1 = *(const floatx4*)(wp + i1 * 2048 + 8);
        w2 = *(const floatx4*)(wp + i1 * 2048 + 16);
        w3 = *(const floatx4*)(wp + i1 * 2048 + 24);

        floatx16 C = __builtin_amdgcn_mfma_f32_32x32x16_f16(ca, cb, zeroC, 0, 0, 0);

#pragma unroll
        for (int r = 0; r < 4; ++r) {
            float av, e2, sg;
            av = C[0 + r];  e2 = __builtin_amdgcn_exp2f(av);
            sg = __builtin_amdgcn_rcpf(1.0f + e2);
            phi = __builtin_fmaf(av * cw0[r], sg, phi);
            av = C[4 + r];  e2 = __builtin_amdgcn_exp2f(av);
            sg = __builtin_amdgcn_rcpf(1.0f + e2);
            phi = __builtin_fmaf(av * cw1[r], sg, phi);
            av = C[8 + r];  e2 = __builtin_amdgcn_exp2f(av);
            sg = __builtin_amdgcn_rcpf(1.0f + e2);
            phi = __builtin_fmaf(av * cw2[r], sg, phi);
            av = C[12 + r]; e2 = __builtin_amdgcn_exp2f(av);
            sg = __builtin_amdgcn_rcpf(1.0f + e2);
            phi = __builtin_fmaf(av * cw3[r], sg, phi);
        }
    }

    // combine the two row-halves (lane and lane^32 share the same column)
    phi += __shfl_xor(phi, 32, 64);

    if (lane < 32) {
        partials[((size_t)ig * B_SZ + btp * 32 + lane) * 64 + o] = phi;
    }
}

// ---------------------------------------------------------------------------
// reduce: out[b,o] = sum_ig partials[ig][b][o] + b2sum[o]; float4-vectorized
// ---------------------------------------------------------------------------
__global__ __launch_bounds__(256) void reduce_kernel(
        const float* __restrict__ partials, const float* __restrict__ b2sum,
        float* __restrict__ out) {
    int t = blockIdx.x * 256 + threadIdx.x;    // < 32768 float4s
    floatx4 s = *(const floatx4*)(b2sum + ((t * 4) & 63));
#pragma unroll
    for (int gg = 0; gg < NIG; ++gg) {
        floatx4 v = *(const floatx4*)(partials + (size_t)gg * (B_SZ * DOUT) + t * 4);
        s += v;
    }
    *(floatx4*)(out + (size_t)t * 4) = s;
}

extern "C" void kernel_launch(void* const* d_in, const int* in_sizes, int n_in,
                              void* d_out, int out_size, void* d_ws, size_t ws_size,
                              hipStream_t stream) {
    const float* x  = (const float*)d_in[0];
    const float* W1 = (const float*)d_in[1];
    const float* W2 = (const float*)d_in[2];
    const float* B1 = (const float*)d_in[3];
    const float* B2 = (const float*)d_in[4];
    float* out = (float*)d_out;

    // ws: w1img (4MB) | fimg (4MB) | w2q (512KB) | b2sum | partials (2MB) | pad
    f16*   w1img    = (f16*)d_ws;
    f16*   fimg     = w1img + W1IMG_ELEMS;
    float* w2q      = (float*)(fimg + FIMG_ELEMS);
    float* b2sum    = w2q + W2Q_ELEMS;
    float* partials = b2sum + 64;

    prep_kernel<<<2561, 256, 0, stream>>>(W1, B1, W2, B2, x, w1img, fimg, w2q, b2sum);
    main_kernel<<<NIG * 32 * 64, 128, 0, stream>>>(w1img, fimg, w2q, partials);
    reduce_kernel<<<(B_SZ * DOUT) / 1024, 256, 0, stream>>>(partials, b2sum, out);
}